// Round 3
// baseline (388.628 us; speedup 1.0000x reference)
//
#include <hip/hip_runtime.h>
#include <cstdint>
#include <cstddef>

// Problem: B=4, S=4096, HID=1024, H=16, DH=64
//   qkv = query @ W^T + b    (M=16384, N=3072, K=1024)
//   per-position (b,s): scores = q(16x64) @ k^T /8 + mask(16x16); softmax; o = p @ v(16x64)
// Pipeline: cast fp32->bf16 (query, W) -> MFMA GEMM (bf16, fp32 acc, +bias, store bf16)
//           -> per-position attention (bf16 K/V staged via global_load_lds) -> out fp32.
// ws layout: Qb bf16 [16M el] @0 ; Wb bf16 [3M el] @33554432 ; QKVb bf16 [48M el] @39845888

typedef __attribute__((ext_vector_type(8))) short bf16x8;
typedef __attribute__((ext_vector_type(4))) float f32x4;

__device__ inline unsigned short f2bf(float f) {
  unsigned int i = __float_as_uint(f);
  i += 0x7fff + ((i >> 16) & 1);   // RNE
  return (unsigned short)(i >> 16);
}

__device__ inline void async16(const void* g, void* l) {
  __builtin_amdgcn_global_load_lds(
      (const __attribute__((address_space(1))) void*)g,
      (__attribute__((address_space(3))) void*)l, 16, 0, 0);
}

// unpack 8 packed bf16 -> 8 fp32
__device__ inline void unpack8(bf16x8 v, float* f) {
  union { bf16x8 s; unsigned int u[4]; } x; x.s = v;
  #pragma unroll
  for (int i = 0; i < 4; ++i) {
    f[2 * i]     = __uint_as_float(x.u[i] << 16);
    f[2 * i + 1] = __uint_as_float(x.u[i] & 0xffff0000u);
  }
}

// ---------------- cast fp32 -> bf16, 4 elems/thread ----------------
__global__ __launch_bounds__(256) void cast_kernel(const float* __restrict__ in,
                                                   unsigned short* __restrict__ out,
                                                   int n) {
  int i = (blockIdx.x * 256 + threadIdx.x) * 4;
  if (i >= n) return;
  float4 v = *(const float4*)(in + i);
  union { unsigned short u[4]; unsigned long long ll; } o;
  o.u[0] = f2bf(v.x); o.u[1] = f2bf(v.y); o.u[2] = f2bf(v.z); o.u[3] = f2bf(v.w);
  *(unsigned long long*)(out + i) = o.ll;
}

// ---------------- GEMM: C[M=16384][N=3072] = A[M][1024] * B[N][1024]^T + bias ----------------
// 128x128 tile, BK=64, 256 threads (4 waves, 2x2 of 64x64), mfma 16x16x32 bf16.
#define GK 1024
#define GN 3072
__global__ __launch_bounds__(256) void gemm_qkv(const unsigned short* __restrict__ A,
                                                const unsigned short* __restrict__ Bm,
                                                const float* __restrict__ bias,
                                                unsigned short* __restrict__ C) {
  __shared__ unsigned short As[128 * 64];
  __shared__ unsigned short Bs[128 * 64];
  const int m0 = blockIdx.x * 128;
  const int n0 = blockIdx.y * 128;
  const int tid  = threadIdx.x;
  const int lane = tid & 63;
  const int wave = tid >> 6;
  const int wm = wave & 1, wn = wave >> 1;       // 2x2 waves, each 64x64
  const int fr = lane & 15;                      // m (A) / n (B) within 16
  const int fq = lane >> 4;                      // quad -> k offset fq*8

  f32x4 acc[4][4] = {};

  for (int k0 = 0; k0 < GK; k0 += 64) {
    #pragma unroll
    for (int t = 0; t < 4; ++t) {
      int sbase = t * 256 + wave * 64;           // wave-uniform slot base
      int sl = sbase + lane;
      int r = sl >> 3;
      int c = (sl & 7) * 8;
      async16(&A[(size_t)(m0 + r) * GK + k0 + c], &As[sbase * 8]);
      async16(&Bm[(size_t)(n0 + r) * GK + k0 + c], &Bs[sbase * 8]);
    }
    __syncthreads();
    #pragma unroll
    for (int ks = 0; ks < 64; ks += 32) {
      bf16x8 af[4], bf[4];
      #pragma unroll
      for (int i = 0; i < 4; ++i) {
        int arow = wm * 64 + i * 16 + fr;
        af[i] = *(const bf16x8*)&As[arow * 64 + ks + fq * 8];
        int brow = wn * 64 + i * 16 + fr;
        bf[i] = *(const bf16x8*)&Bs[brow * 64 + ks + fq * 8];
      }
      #pragma unroll
      for (int i = 0; i < 4; ++i)
        #pragma unroll
        for (int j = 0; j < 4; ++j)
          acc[i][j] = __builtin_amdgcn_mfma_f32_16x16x32_bf16(af[i], bf[j], acc[i][j], 0, 0, 0);
    }
    __syncthreads();
  }

  #pragma unroll
  for (int i = 0; i < 4; ++i) {
    #pragma unroll
    for (int j = 0; j < 4; ++j) {
      int col = n0 + wn * 64 + j * 16 + fr;
      float bc = bias[col];
      #pragma unroll
      for (int r = 0; r < 4; ++r) {
        int row = m0 + wm * 64 + i * 16 + fq * 4 + r;
        C[(size_t)row * GN + col] = f2bf(acc[i][j][r] + bc);
      }
    }
  }
}

// ---------------- per-position attention ----------------
// one wave per position; lane = h*4 + dg (h = lane>>2, dg = lane&3).
// K/V staged to LDS as bf16 via global_load_lds (wave-private region, no syncthreads).
// q and mask read straight from global (coalesced). All LDS reads are b128,
// bank quads {0,8,16,24} across dg -> conflict-free with 16-lane broadcast.
__global__ __launch_bounds__(256) void attn_kernel(const unsigned short* __restrict__ QKV,
                                                   const float* __restrict__ mask,
                                                   float* __restrict__ out) {
  __shared__ unsigned short shKV[4][2048];   // per wave: K [0..1023], V [1024..2047]
  const int wave = threadIdx.x >> 6;
  const int lane = threadIdx.x & 63;
  const int pos = blockIdx.x * 4 + wave;

  const unsigned short* row = QKV + (size_t)pos * 3072;

  // ---- stage K+V (2048 bf16 = 4 KB) via 4 DMA chunks: lds[t*512+lane*8] = row[1024+t*512+lane*8]
  #pragma unroll
  for (int t = 0; t < 4; ++t)
    async16(&row[1024 + t * 512 + (size_t)lane * 8], &shKV[wave][t * 512]);

  // ---- q slice from global: row[lane*16 .. +16)  (coalesced 32B/lane)
  bf16x8 q0 = *(const bf16x8*)&row[lane * 16];
  bf16x8 q1 = *(const bf16x8*)&row[lane * 16 + 8];

  const int h = lane >> 2;
  const int dg = lane & 3;

  // ---- mask row (float4 x4); 4 lanes per h broadcast the same address
  const float* mrow = mask + (size_t)pos * 256 + h * 16;
  float4 m4[4];
  #pragma unroll
  for (int t = 0; t < 4; ++t) m4[t] = *(const float4*)&mrow[t * 4];

  float q[16];
  unpack8(q0, q);
  unpack8(q1, q + 8);

  // wait for the LDS DMA (and everything else) before touching LDS
  asm volatile("s_waitcnt vmcnt(0)" ::: "memory");

  // ---- partial scores over this lane's 16 d's
  float s[16];
  #pragma unroll
  for (int g = 0; g < 16; ++g) {
    const unsigned short* kp = &shKV[wave][g * 64 + dg * 16];
    float kf[16];
    unpack8(*(const bf16x8*)kp, kf);
    unpack8(*(const bf16x8*)(kp + 8), kf + 8);
    float acc = 0.f;
    #pragma unroll
    for (int d = 0; d < 16; ++d) acc += q[d] * kf[d];
    s[g] = acc;
  }
  // reduce across the 4 dg lanes
  #pragma unroll
  for (int g = 0; g < 16; ++g) {
    s[g] += __shfl_xor(s[g], 1);
    s[g] += __shfl_xor(s[g], 2);
  }

  // ---- scale + mask + softmax
  const float* mp = (const float*)m4;
  float mx = -1e30f;
  #pragma unroll
  for (int g = 0; g < 16; ++g) {
    s[g] = s[g] * 0.125f + mp[g];
    mx = fmaxf(mx, s[g]);
  }
  float sum = 0.f;
  #pragma unroll
  for (int g = 0; g < 16; ++g) { s[g] = __expf(s[g] - mx); sum += s[g]; }
  float inv = 1.f / sum;

  // ---- o[h][dg*16+dd] = sum_g p[g] * v[g][dg*16+dd]
  float o[16];
  #pragma unroll
  for (int dd = 0; dd < 16; ++dd) o[dd] = 0.f;
  #pragma unroll
  for (int g = 0; g < 16; ++g) {
    const unsigned short* vp = &shKV[wave][1024 + g * 64 + dg * 16];
    float vf[16];
    unpack8(*(const bf16x8*)vp, vf);
    unpack8(*(const bf16x8*)(vp + 8), vf + 8);
    float p = s[g];
    #pragma unroll
    for (int dd = 0; dd < 16; ++dd) o[dd] += p * vf[dd];
  }

  // ---- store: out[pos*1024 + lane*16 .. +16)  (coalesced)
  float* op = out + (size_t)pos * 1024 + lane * 16;
  #pragma unroll
  for (int t = 0; t < 4; ++t) {
    float4 w;
    w.x = o[t * 4 + 0] * inv; w.y = o[t * 4 + 1] * inv;
    w.z = o[t * 4 + 2] * inv; w.w = o[t * 4 + 3] * inv;
    *(float4*)(op + t * 4) = w;
  }
}

extern "C" void kernel_launch(void* const* d_in, const int* in_sizes, int n_in,
                              void* d_out, int out_size, void* d_ws, size_t ws_size,
                              hipStream_t stream) {
  const float* query = (const float*)d_in[0];
  // d_in[1] (key) and d_in[2] (value) are unused by the reference.
  const float* mask  = (const float*)d_in[3];
  const float* Wqkv  = (const float*)d_in[4];
  const float* bqkv  = (const float*)d_in[5];
  float* out = (float*)d_out;

  unsigned short* qb   = (unsigned short*)d_ws;                                  // 16,777,216 el
  unsigned short* wb   = (unsigned short*)((char*)d_ws + 33554432);              //  3,145,728 el
  unsigned short* qkvb = (unsigned short*)((char*)d_ws + 39845888);              // 50,331,648 el

  cast_kernel<<<16384, 256, 0, stream>>>(query, qb, 16777216);
  cast_kernel<<<3072, 256, 0, stream>>>(Wqkv, wb, 3145728);

  dim3 g(128, 24);
  gemm_qkv<<<g, 256, 0, stream>>>(qb, wb, bqkv, qkvb);

  attn_kernel<<<4096, 256, 0, stream>>>(qkvb, mask, out);
}

// Round 4
// 358.557 us; speedup vs baseline: 1.0839x; 1.0839x over previous
//
#include <hip/hip_runtime.h>
#include <cstdint>
#include <cstddef>

// Problem: B=4, S=4096, HID=1024, H=16, DH=64
//   qkv = query @ W^T + b    (M=16384, N=3072, K=1024)
//   per-position (b,s): scores = q(16x64) @ k^T /8 + mask(16x16); softmax; o = p @ v(16x64)
// Pipeline: cast fp32->bf16 (query, W) -> MFMA GEMM (bf16, fp32 acc, +bias, store bf16)
//           -> per-position attention (bf16 K/V staged via global_load_lds) -> out fp32.
// GEMM LDS tiles are XOR-swizzled at 16B-chunk granularity (slot = chunk ^ (row&7))
// to spread fragment reads across all 8 bank quads (was: 16-way same-quad, 3.8e7
// conflict cycles = ~36% of gemm time). Swizzle is applied in the global source
// address of the DMA staging, undone at fragment-read time.
// ws layout: Qb bf16 [16M el] @0 ; Wb bf16 [3M el] @33554432 ; QKVb bf16 [48M el] @39845888

typedef __attribute__((ext_vector_type(8))) short bf16x8;
typedef __attribute__((ext_vector_type(4))) float f32x4;

__device__ inline unsigned short f2bf(float f) {
  unsigned int i = __float_as_uint(f);
  i += 0x7fff + ((i >> 16) & 1);   // RNE
  return (unsigned short)(i >> 16);
}

__device__ inline void async16(const void* g, void* l) {
  __builtin_amdgcn_global_load_lds(
      (const __attribute__((address_space(1))) void*)g,
      (__attribute__((address_space(3))) void*)l, 16, 0, 0);
}

// unpack 8 packed bf16 -> 8 fp32
__device__ inline void unpack8(bf16x8 v, float* f) {
  union { bf16x8 s; unsigned int u[4]; } x; x.s = v;
  #pragma unroll
  for (int i = 0; i < 4; ++i) {
    f[2 * i]     = __uint_as_float(x.u[i] << 16);
    f[2 * i + 1] = __uint_as_float(x.u[i] & 0xffff0000u);
  }
}

// ---------------- cast fp32 -> bf16, 4 elems/thread ----------------
__global__ __launch_bounds__(256) void cast_kernel(const float* __restrict__ in,
                                                   unsigned short* __restrict__ out,
                                                   int n) {
  int i = (blockIdx.x * 256 + threadIdx.x) * 4;
  if (i >= n) return;
  float4 v = *(const float4*)(in + i);
  union { unsigned short u[4]; unsigned long long ll; } o;
  o.u[0] = f2bf(v.x); o.u[1] = f2bf(v.y); o.u[2] = f2bf(v.z); o.u[3] = f2bf(v.w);
  *(unsigned long long*)(out + i) = o.ll;
}

// ---------------- GEMM: C[M=16384][N=3072] = A[M][1024] * B[N][1024]^T + bias ----------------
// 128x128 tile, BK=64, 256 threads (4 waves, 2x2 of 64x64), mfma 16x16x32 bf16.
#define GK 1024
#define GN 3072
__global__ __launch_bounds__(256) void gemm_qkv(const unsigned short* __restrict__ A,
                                                const unsigned short* __restrict__ Bm,
                                                const float* __restrict__ bias,
                                                unsigned short* __restrict__ C) {
  __shared__ unsigned short As[128 * 64];
  __shared__ unsigned short Bs[128 * 64];
  const int m0 = blockIdx.x * 128;
  const int n0 = blockIdx.y * 128;
  const int tid  = threadIdx.x;
  const int lane = tid & 63;
  const int wave = tid >> 6;
  const int wm = wave & 1, wn = wave >> 1;       // 2x2 waves, each 64x64
  const int fr = lane & 15;                      // m (A) / n (B) within 16
  const int fq = lane >> 4;                      // quad -> k offset fq*8

  f32x4 acc[4][4] = {};

  for (int k0 = 0; k0 < GK; k0 += 64) {
    // stage A,B tiles: slot sl holds row r = sl>>3, k-chunk c = (sl&7) ^ (r&7).
    // 8 lanes covering one row read a permuted-but-complete 128B segment: coalesced.
    #pragma unroll
    for (int t = 0; t < 4; ++t) {
      int sbase = t * 256 + wave * 64;           // wave-uniform slot base (mult of 8)
      int sl = sbase + lane;
      int r = sl >> 3;
      int c = ((sl & 7) ^ (r & 7)) * 8;          // XOR bank-quad swizzle
      async16(&A[(size_t)(m0 + r) * GK + k0 + c], &As[sbase * 8]);
      async16(&Bm[(size_t)(n0 + r) * GK + k0 + c], &Bs[sbase * 8]);
    }
    __syncthreads();
    #pragma unroll
    for (int ks = 0; ks < 64; ks += 32) {
      const int cbase = ks >> 3;                 // 0 or 4
      bf16x8 af[4], bf[4];
      #pragma unroll
      for (int i = 0; i < 4; ++i) {
        int arow = wm * 64 + i * 16 + fr;
        int ac = (cbase + fq) ^ (arow & 7);      // un-swizzle
        af[i] = *(const bf16x8*)&As[arow * 64 + ac * 8];
        int brow = wn * 64 + i * 16 + fr;
        int bc = (cbase + fq) ^ (brow & 7);
        bf[i] = *(const bf16x8*)&Bs[brow * 64 + bc * 8];
      }
      #pragma unroll
      for (int i = 0; i < 4; ++i)
        #pragma unroll
        for (int j = 0; j < 4; ++j)
          acc[i][j] = __builtin_amdgcn_mfma_f32_16x16x32_bf16(af[i], bf[j], acc[i][j], 0, 0, 0);
    }
    __syncthreads();
  }

  #pragma unroll
  for (int i = 0; i < 4; ++i) {
    #pragma unroll
    for (int j = 0; j < 4; ++j) {
      int col = n0 + wn * 64 + j * 16 + fr;
      float bc = bias[col];
      #pragma unroll
      for (int r = 0; r < 4; ++r) {
        int row = m0 + wm * 64 + i * 16 + fq * 4 + r;
        C[(size_t)row * GN + col] = f2bf(acc[i][j][r] + bc);
      }
    }
  }
}

// ---------------- per-position attention ----------------
// one wave per position; lane = h*4 + dg (h = lane>>2, dg = lane&3).
// K/V staged to LDS as bf16 via global_load_lds (wave-private region, no syncthreads).
__global__ __launch_bounds__(256) void attn_kernel(const unsigned short* __restrict__ QKV,
                                                   const float* __restrict__ mask,
                                                   float* __restrict__ out) {
  __shared__ unsigned short shKV[4][2048];   // per wave: K [0..1023], V [1024..2047]
  const int wave = threadIdx.x >> 6;
  const int lane = threadIdx.x & 63;
  const int pos = blockIdx.x * 4 + wave;

  const unsigned short* row = QKV + (size_t)pos * 3072;

  // ---- stage K+V (2048 bf16 = 4 KB) via 4 DMA chunks
  #pragma unroll
  for (int t = 0; t < 4; ++t)
    async16(&row[1024 + t * 512 + (size_t)lane * 8], &shKV[wave][t * 512]);

  // ---- q slice from global: row[lane*16 .. +16)  (coalesced 32B/lane)
  bf16x8 q0 = *(const bf16x8*)&row[lane * 16];
  bf16x8 q1 = *(const bf16x8*)&row[lane * 16 + 8];

  const int h = lane >> 2;
  const int dg = lane & 3;

  const float* mrow = mask + (size_t)pos * 256 + h * 16;
  float4 m4[4];
  #pragma unroll
  for (int t = 0; t < 4; ++t) m4[t] = *(const float4*)&mrow[t * 4];

  float q[16];
  unpack8(q0, q);
  unpack8(q1, q + 8);

  asm volatile("s_waitcnt vmcnt(0)" ::: "memory");

  float s[16];
  #pragma unroll
  for (int g = 0; g < 16; ++g) {
    const unsigned short* kp = &shKV[wave][g * 64 + dg * 16];
    float kf[16];
    unpack8(*(const bf16x8*)kp, kf);
    unpack8(*(const bf16x8*)(kp + 8), kf + 8);
    float acc = 0.f;
    #pragma unroll
    for (int d = 0; d < 16; ++d) acc += q[d] * kf[d];
    s[g] = acc;
  }
  #pragma unroll
  for (int g = 0; g < 16; ++g) {
    s[g] += __shfl_xor(s[g], 1);
    s[g] += __shfl_xor(s[g], 2);
  }

  const float* mp = (const float*)m4;
  float mx = -1e30f;
  #pragma unroll
  for (int g = 0; g < 16; ++g) {
    s[g] = s[g] * 0.125f + mp[g];
    mx = fmaxf(mx, s[g]);
  }
  float sum = 0.f;
  #pragma unroll
  for (int g = 0; g < 16; ++g) { s[g] = __expf(s[g] - mx); sum += s[g]; }
  float inv = 1.f / sum;

  float o[16];
  #pragma unroll
  for (int dd = 0; dd < 16; ++dd) o[dd] = 0.f;
  #pragma unroll
  for (int g = 0; g < 16; ++g) {
    const unsigned short* vp = &shKV[wave][1024 + g * 64 + dg * 16];
    float vf[16];
    unpack8(*(const bf16x8*)vp, vf);
    unpack8(*(const bf16x8*)(vp + 8), vf + 8);
    float p = s[g];
    #pragma unroll
    for (int dd = 0; dd < 16; ++dd) o[dd] += p * vf[dd];
  }

  float* op = out + (size_t)pos * 1024 + lane * 16;
  #pragma unroll
  for (int t = 0; t < 4; ++t) {
    float4 w;
    w.x = o[t * 4 + 0] * inv; w.y = o[t * 4 + 1] * inv;
    w.z = o[t * 4 + 2] * inv; w.w = o[t * 4 + 3] * inv;
    *(float4*)(op + t * 4) = w;
  }
}

extern "C" void kernel_launch(void* const* d_in, const int* in_sizes, int n_in,
                              void* d_out, int out_size, void* d_ws, size_t ws_size,
                              hipStream_t stream) {
  const float* query = (const float*)d_in[0];
  // d_in[1] (key) and d_in[2] (value) are unused by the reference.
  const float* mask  = (const float*)d_in[3];
  const float* Wqkv  = (const float*)d_in[4];
  const float* bqkv  = (const float*)d_in[5];
  float* out = (float*)d_out;

  unsigned short* qb   = (unsigned short*)d_ws;                                  // 16,777,216 el
  unsigned short* wb   = (unsigned short*)((char*)d_ws + 33554432);              //  3,145,728 el
  unsigned short* qkvb = (unsigned short*)((char*)d_ws + 39845888);              // 50,331,648 el

  cast_kernel<<<16384, 256, 0, stream>>>(query, qb, 16777216);
  cast_kernel<<<3072, 256, 0, stream>>>(Wqkv, wb, 3145728);

  dim3 g(128, 24);
  gemm_qkv<<<g, 256, 0, stream>>>(qb, wb, bqkv, qkvb);

  attn_kernel<<<4096, 256, 0, stream>>>(qkvb, mask, out);
}